// Round 16
// baseline (321.252 us; speedup 1.0000x reference)
//
#include <hip/hip_runtime.h>
#include <stdint.h>

#define LEN_T 13294
#define M_TOK 53176   // 4 * 13294

typedef unsigned short u16;
typedef __bf16 bf16x8 __attribute__((ext_vector_type(8)));
typedef float f32x4 __attribute__((ext_vector_type(4)));
typedef float f32x2 __attribute__((ext_vector_type(2)));
typedef uint32_t u32x4 __attribute__((ext_vector_type(4)));
typedef uint32_t u32x2 __attribute__((ext_vector_type(2)));
typedef _Float16 h16x2 __attribute__((ext_vector_type(2)));

__device__ __forceinline__ u16 f2bf(float f) {
    union { float f; uint32_t u; } v; v.f = f;
    uint32_t r = v.u + 0x7fffu + ((v.u >> 16) & 1u);
    return (u16)(r >> 16);
}
__device__ __forceinline__ float bf2f(u16 s) {
    union { uint32_t u; float f; } v; v.u = ((uint32_t)s) << 16;
    return v.f;
}
__device__ __forceinline__ u16 f2h(float f) {
    union { _Float16 h; u16 u; } c; c.h = (_Float16)f; return c.u;
}
__device__ __forceinline__ float hlo(uint32_t u) {
    union { uint32_t u; _Float16 h[2]; } v; v.u = u; return (float)v.h[0];
}
__device__ __forceinline__ float hhi(uint32_t u) {
    union { uint32_t u; _Float16 h[2]; } v; v.u = u; return (float)v.h[1];
}
__device__ __forceinline__ h16x2 u2h(uint32_t u) {
    union { uint32_t u; h16x2 h; } c; c.u = u; return c.h;
}

__device__ __forceinline__ void gload_lds16(const u16* g, u16* l) {
    __builtin_amdgcn_global_load_lds(
        (const __attribute__((address_space(1))) uint32_t*)(g),
        (__attribute__((address_space(3))) uint32_t*)(l), 16, 0, 0);
}

// ---------------- prep + all weight transposes, ONE launch ---------------------
__global__ __launch_bounds__(256) void prep_wtrans(
    const float* __restrict__ feat, const float* __restrict__ pos,
    u16* __restrict__ qb, u16* __restrict__ fb, int n4,
    const float* __restrict__ W_val, const float* __restrict__ W_off,
    const float* __restrict__ W_attn, const float* __restrict__ W_out,
    const float* __restrict__ W1, const float* __restrict__ W2,
    u16* __restrict__ Wt_val, u16* __restrict__ Wt_oa,
    u16* __restrict__ Wt_out, u16* __restrict__ W1f, u16* __restrict__ W2f)
{
    if (blockIdx.x < 2048) {
        int i = blockIdx.x * 256 + threadIdx.x;
        int stride = 2048 * 256;
        for (; i < n4; i += stride) {
            float4 f = ((const float4*)feat)[i];
            float4 p = ((const float4*)pos)[i];
            uint32_t q0 = (uint32_t)f2bf(f.x + p.x) | ((uint32_t)f2bf(f.y + p.y) << 16);
            uint32_t q1 = (uint32_t)f2bf(f.z + p.z) | ((uint32_t)f2bf(f.w + p.w) << 16);
            uint32_t f0 = (uint32_t)f2bf(f.x) | ((uint32_t)f2bf(f.y) << 16);
            uint32_t f1 = (uint32_t)f2bf(f.z) | ((uint32_t)f2bf(f.w) << 16);
            ((uint2*)qb)[i] = make_uint2(q0, q1);
            ((uint2*)fb)[i] = make_uint2(f0, f1);
        }
        return;
    }
    int gid = (blockIdx.x - 2048) * 256 + threadIdx.x;
    if (gid < 229376) {
        const float* W; u16* D; int K, N, off;
        if      (gid < 65536)  { W = W_val;  D = Wt_val;        K = 256; N = 256; off = gid; }
        else if (gid < 131072) { W = W_off;  D = Wt_oa;         K = 256; N = 256; off = gid - 65536; }
        else if (gid < 163840) { W = W_attn; D = Wt_oa + 65536; K = 256; N = 128; off = gid - 131072; }
        else                   { W = W_out;  D = Wt_out;        K = 256; N = 256; off = gid - 163840; }
        int n = off / K, k = off - n * K;
        D[off] = f2bf(W[(size_t)k * N + n]);
    } else if (gid < 491520) {
        int off = gid - 229376;
        int e = off & 7, lane = (off >> 3) & 63;
        int r = off >> 9;
        int ks = r & 7, ni = (r >> 3) & 1, c = r >> 4;
        int col = c * 32 + ni * 16 + (lane & 15);
        int k = ks * 32 + (lane >> 4) * 8 + e;
        W1f[off] = f2bf(W1[(size_t)k * 1024 + col]);
    } else if (gid < 753664) {
        int off = gid - 491520;
        int e = off & 7, lane = (off >> 3) & 63;
        int r = off >> 9;
        int col = (r & 15) * 16 + (lane & 15);
        int k = (r >> 4) * 32 + (lane >> 4) * 8 + e;
        W2f[off] = f2bf(W2[(size_t)k * 256 + col]);
    }
}

// ---------------- merged VAL + OFFATTN 128x128 GEMM (one dispatch, y=0..4) -----
__global__ __launch_bounds__(256, 4) void gemm_va(
    const u16* __restrict__ fb, const u16* __restrict__ qb,
    const u16* __restrict__ Wt_val, const u16* __restrict__ Wt_oa,
    int M,
    const float* __restrict__ b_val, const float* __restrict__ b_off,
    const float* __restrict__ b_attn,
    u16* __restrict__ value, u16* __restrict__ offt, u16* __restrict__ attnt)
{
    __shared__ u16 Al[128 * 64];
    __shared__ u16 Bl[128 * 64];
    const int tid = threadIdx.x;
    const int lane = tid & 63;
    const int w = tid >> 6;
    const int wr = w >> 1, wc = w & 1;
    const int m0 = blockIdx.x * 128;
    const bool isval = blockIdx.y < 2;
    const int n0 = (isval ? blockIdx.y : blockIdx.y - 2) * 128;
    const u16* A  = isval ? fb : qb;
    const u16* Bt = isval ? Wt_val : Wt_oa;
    const int l15 = lane & 15;
    const int kg = lane >> 4;
    const int srow = lane >> 3;
    const int scol = (lane & 7) * 8;

    f32x4 acc[4][4];
#pragma unroll
    for (int i = 0; i < 4; ++i)
#pragma unroll
        for (int j = 0; j < 4; ++j)
            acc[i][j] = (f32x4){0.f, 0.f, 0.f, 0.f};

    for (int kc = 0; kc < 4; ++kc) {
        __syncthreads();
#pragma unroll
        for (int j = 0; j < 4; ++j) {
            int c = w * 4 + j;
            int arow = m0 + c * 8 + srow;
            arow = arow < M ? arow : M - 1;
            gload_lds16(A + (size_t)arow * 256 + (kc << 6) + scol, Al + c * 512);
            int brow = n0 + c * 8 + srow;
            gload_lds16(Bt + (size_t)brow * 256 + (kc << 6) + scol, Bl + c * 512);
        }
        __syncthreads();
#pragma unroll
        for (int ks = 0; ks < 2; ++ks) {
            bf16x8 af[4], bfr[4];
#pragma unroll
            for (int i = 0; i < 4; ++i) {
                af[i]  = *(const bf16x8*)(Al + (wr * 64 + i * 16 + l15) * 64 + ks * 32 + kg * 8);
                bfr[i] = *(const bf16x8*)(Bl + (wc * 64 + i * 16 + l15) * 64 + ks * 32 + kg * 8);
            }
#pragma unroll
            for (int mi = 0; mi < 4; ++mi)
#pragma unroll
                for (int ni = 0; ni < 4; ++ni)
                    acc[mi][ni] = __builtin_amdgcn_mfma_f32_16x16x32_bf16(
                        af[mi], bfr[ni], acc[mi][ni], 0, 0, 0);
        }
    }

#pragma unroll
    for (int mi = 0; mi < 4; ++mi) {
#pragma unroll
        for (int r = 0; r < 4; ++r) {
            int row = m0 + wr * 64 + mi * 16 + kg * 4 + r;
            if (row >= M) continue;
#pragma unroll
            for (int ni = 0; ni < 4; ++ni) {
                int col = n0 + wc * 64 + ni * 16 + l15;
                float v = acc[mi][ni][r];
                if (isval) {
                    int bI = row / LEN_T;
                    int t = row - bI * LEN_T;
                    int hh = col >> 5, d = col & 31;
                    value[((size_t)(bI * 8 + hh) * LEN_T + t) * 32 + d] =
                        f2h(v + b_val[col]);
                } else {
                    if (col < 256) {
                        offt[((size_t)(col >> 5) * M_TOK + row) * 32 + (col & 31)] =
                            f2h(v + b_off[col]);
                    } else {
                        int c = col - 256;
                        attnt[((size_t)(c >> 4) * M_TOK + row) * 16 + (c & 15)] =
                            f2h(v + b_attn[c]);
                    }
                }
            }
        }
    }
}

// ---------------- 64-row GEMM + LayerNorm epilogue (W_out + LN1), bf16 dump ----
template<int KSTEPS, int OUTF32>
__global__ __launch_bounds__(256, 3) void gemm_ln(
    const u16* __restrict__ A, const u16* __restrict__ Bt,
    const float* __restrict__ bias, const u16* __restrict__ res,
    const float* __restrict__ g, const float* __restrict__ bb,
    u16* __restrict__ outb, float* __restrict__ outf, int M)
{
    __shared__ char ldsraw[40960];
    u16* Al = (u16*)ldsraw;                 // [64][64]
    u16* Bl = (u16*)(ldsraw + 8192);        // [256][64]
    u16* dumpb = (u16*)ldsraw;              // [64][264] bf16 (aliases stage bufs)
    const int tid = threadIdx.x;
    const int lane = tid & 63;
    const int w = tid >> 6;
    const int l15 = lane & 15;
    const int kg = lane >> 4;
    const int srow = lane >> 3;
    const int scol = (lane & 7) * 8;
    const int m0 = blockIdx.x * 64;
    const int K = KSTEPS * 64;

    f32x4 acc[4][4];
#pragma unroll
    for (int i = 0; i < 4; ++i)
#pragma unroll
        for (int j = 0; j < 4; ++j)
            acc[i][j] = (f32x4){0.f, 0.f, 0.f, 0.f};

    for (int kc = 0; kc < KSTEPS; ++kc) {
        __syncthreads();
#pragma unroll
        for (int j = 0; j < 2; ++j) {
            int c = w * 2 + j;
            int arow = m0 + c * 8 + srow;
            arow = arow < M ? arow : M - 1;
            gload_lds16(A + (size_t)arow * K + (kc << 6) + scol, Al + c * 512);
        }
#pragma unroll
        for (int j = 0; j < 8; ++j) {
            int c = w * 8 + j;
            int brow = c * 8 + srow;
            gload_lds16(Bt + (size_t)brow * K + (kc << 6) + scol, Bl + c * 512);
        }
        __syncthreads();
#pragma unroll
        for (int ks = 0; ks < 2; ++ks) {
            bf16x8 af[4], bfr[4];
#pragma unroll
            for (int i = 0; i < 4; ++i) {
                af[i]  = *(const bf16x8*)(Al + (i * 16 + l15) * 64 + ks * 32 + kg * 8);
                bfr[i] = *(const bf16x8*)(Bl + (w * 64 + i * 16 + l15) * 64 + ks * 32 + kg * 8);
            }
#pragma unroll
            for (int mi = 0; mi < 4; ++mi)
#pragma unroll
                for (int ni = 0; ni < 4; ++ni)
                    acc[mi][ni] = __builtin_amdgcn_mfma_f32_16x16x32_bf16(
                        af[mi], bfr[ni], acc[mi][ni], 0, 0, 0);
        }
    }

    __syncthreads();   // staging reads done before dump overwrites Al/Bl
#pragma unroll
    for (int mi = 0; mi < 4; ++mi) {
#pragma unroll
        for (int r = 0; r < 4; ++r) {
            int rr = mi * 16 + kg * 4 + r;
            int gr = m0 + rr; gr = gr < M ? gr : M - 1;
#pragma unroll
            for (int ni = 0; ni < 4; ++ni) {
                int col = w * 64 + ni * 16 + l15;
                dumpb[rr * 264 + col] = f2bf(acc[mi][ni][r] + bias[col] +
                                             bf2f(res[(size_t)gr * 256 + col]));
            }
        }
    }
    __syncthreads();

    float4 gv = *(const float4*)(g + lane * 4);
    float4 bv = *(const float4*)(bb + lane * 4);
#pragma unroll
    for (int i = 0; i < 16; ++i) {
        int rr = w * 16 + i;
        uint2 raw = *(const uint2*)(dumpb + rr * 264 + lane * 4);
        float x0 = bf2f((u16)(raw.x & 0xffff)), x1 = bf2f((u16)(raw.x >> 16));
        float x2 = bf2f((u16)(raw.y & 0xffff)), x3 = bf2f((u16)(raw.y >> 16));
        float s1 = x0 + x1 + x2 + x3;
        float s2 = x0*x0 + x1*x1 + x2*x2 + x3*x3;
#pragma unroll
        for (int o = 1; o < 64; o <<= 1) {
            s1 += __shfl_xor(s1, o);
            s2 += __shfl_xor(s2, o);
        }
        float mu = s1 * (1.0f / 256.0f);
        float var = s2 * (1.0f / 256.0f) - mu * mu;
        float rs = rsqrtf(var + 1e-5f);
        float o0 = (x0 - mu) * rs * gv.x + bv.x;
        float o1 = (x1 - mu) * rs * gv.y + bv.y;
        float o2 = (x2 - mu) * rs * gv.z + bv.z;
        float o3 = (x3 - mu) * rs * gv.w + bv.w;
        int grow = m0 + rr;
        if (grow < M) {
            if (OUTF32) {
                *(float4*)(outf + (size_t)grow * 256 + lane * 4) =
                    make_float4(o0, o1, o2, o3);
            } else {
                uint32_t u0 = (uint32_t)f2bf(o0) | ((uint32_t)f2bf(o1) << 16);
                uint32_t u1 = (uint32_t)f2bf(o2) | ((uint32_t)f2bf(o3) << 16);
                *(uint2*)(outb + (size_t)grow * 256 + lane * 4) = make_uint2(u0, u1);
            }
        }
    }
}

// ---------------- fused FFN (round-9 proven structure) -------------------------
__global__ __launch_bounds__(256, 3) void ffn_fused(
    const u16* __restrict__ A, const u16* __restrict__ W1f, const u16* __restrict__ W2f,
    const float* __restrict__ b1, const float* __restrict__ b2,
    const float* __restrict__ g, const float* __restrict__ bb,
    float* __restrict__ outf, int M)
{
    __shared__ char lds[51200];
    u16* Axl = (u16*)lds;                 // [64][264] bf16 (x staging + residual)
    u16* ht  = (u16*)(lds + 33792);       // [64][136] bf16
    u16* dumpb = (u16*)lds;               // [64][264] bf16 (aliases Axl)
    const int tid = threadIdx.x;
    const int lane = tid & 63;
    const int w = tid >> 6;
    const int l15 = lane & 15;
    const int kg = lane >> 4;
    const int m0 = blockIdx.x * 64;

#pragma unroll
    for (int i = 0; i < 8; ++i) {
        int linear = i * 256 + tid;
        int row = linear >> 5;
        int gcol = (linear & 31) * 8;
        int grow = m0 + row; grow = grow < M ? grow : M - 1;
        uint4 v = *(const uint4*)(A + (size_t)grow * 256 + gcol);
        *(uint4*)(Axl + row * 264 + gcol) = v;
    }
    __syncthreads();

    f32x4 acc[4][4];
#pragma unroll
    for (int i = 0; i < 4; ++i)
#pragma unroll
        for (int j = 0; j < 4; ++j)
            acc[i][j] = (f32x4){0.f, 0.f, 0.f, 0.f};
    f32x4 acc2[4][2];

#define ZERO_ACC2() \
    _Pragma("unroll") for (int i = 0; i < 4; ++i) { \
        acc2[i][0] = (f32x4){0.f,0.f,0.f,0.f}; acc2[i][1] = (f32x4){0.f,0.f,0.f,0.f}; }

#define FFN1_CHUNK(HC) { \
    _Pragma("unroll") for (int ks = 0; ks < 8; ++ks) { \
        bf16x8 af[4], bw[2]; \
        _Pragma("unroll") for (int ni = 0; ni < 2; ++ni) \
            bw[ni] = *(const bf16x8*)(W1f + ((size_t)(((((HC) * 4 + w) * 2 + ni) * 8 + ks)) << 9) + lane * 8); \
        _Pragma("unroll") for (int mi = 0; mi < 4; ++mi) \
            af[mi] = *(const bf16x8*)(Axl + (mi * 16 + l15) * 264 + ks * 32 + kg * 8); \
        _Pragma("unroll") for (int mi = 0; mi < 4; ++mi) \
            _Pragma("unroll") for (int ni = 0; ni < 2; ++ni) \
                acc2[mi][ni] = __builtin_amdgcn_mfma_f32_16x16x32_bf16(af[mi], bw[ni], acc2[mi][ni], 0, 0, 0); \
    } }

#define FFN2_CHUNK(HC) { \
    _Pragma("unroll") for (int ks2 = 0; ks2 < 4; ++ks2) { \
        bf16x8 ah[4], bw2[4]; \
        _Pragma("unroll") for (int ni = 0; ni < 4; ++ni) \
            bw2[ni] = *(const bf16x8*)(W2f + ((size_t)((((HC) * 4 + ks2) * 16 + w * 4 + ni)) << 9) + lane * 8); \
        _Pragma("unroll") for (int mi = 0; mi < 4; ++mi) \
            ah[mi] = *(const bf16x8*)(ht + (mi * 16 + l15) * 136 + ks2 * 32 + kg * 8); \
        _Pragma("unroll") for (int mi = 0; mi < 4; ++mi) \
            _Pragma("unroll") for (int ni = 0; ni < 4; ++ni) \
                acc[mi][ni] = __builtin_amdgcn_mfma_f32_16x16x32_bf16(ah[mi], bw2[ni], acc[mi][ni], 0, 0, 0); \
    } }

#define HT_WRITE(HC) { \
    _Pragma("unroll") for (int mi = 0; mi < 4; ++mi) \
        _Pragma("unroll") for (int ni = 0; ni < 2; ++ni) \
            _Pragma("unroll") for (int r = 0; r < 4; ++r) { \
                int rr = mi * 16 + kg * 4 + r; \
                int cl = w * 32 + ni * 16 + l15; \
                float hv = acc2[mi][ni][r] + b1[(HC) * 128 + cl]; \
                ht[rr * 136 + cl] = f2bf(hv > 0.f ? hv : 0.f); \
            } }

    ZERO_ACC2();
    FFN1_CHUNK(0);
    for (int hc = 0; hc < 8; ++hc) {
        __syncthreads();
        HT_WRITE(hc);
        __syncthreads();
        FFN2_CHUNK(hc);
        if (hc < 7) { ZERO_ACC2(); FFN1_CHUNK(hc + 1); }
    }

#pragma unroll
    for (int mi = 0; mi < 4; ++mi) {
#pragma unroll
        for (int r = 0; r < 4; ++r) {
            int rr = mi * 16 + kg * 4 + r;
#pragma unroll
            for (int ni = 0; ni < 4; ++ni) {
                int col = w * 64 + ni * 16 + l15;
                float v = acc[mi][ni][r] + b2[col] + bf2f(Axl[rr * 264 + col]);
                dumpb[rr * 264 + col] = f2bf(v);
            }
        }
    }
    __syncthreads();

    float4 gv = *(const float4*)(g + lane * 4);
    float4 bv = *(const float4*)(bb + lane * 4);
#pragma unroll
    for (int i = 0; i < 16; ++i) {
        int rr = w * 16 + i;
        uint2 raw = *(const uint2*)(dumpb + rr * 264 + lane * 4);
        float x0 = bf2f((u16)(raw.x & 0xffff)), x1 = bf2f((u16)(raw.x >> 16));
        float x2 = bf2f((u16)(raw.y & 0xffff)), x3 = bf2f((u16)(raw.y >> 16));
        float s1 = x0 + x1 + x2 + x3;
        float s2 = x0*x0 + x1*x1 + x2*x2 + x3*x3;
#pragma unroll
        for (int o = 1; o < 64; o <<= 1) {
            s1 += __shfl_xor(s1, o);
            s2 += __shfl_xor(s2, o);
        }
        float mu = s1 * (1.0f / 256.0f);
        float var = s2 * (1.0f / 256.0f) - mu * mu;
        float rs = rsqrtf(var + 1e-5f);
        float o0 = (x0 - mu) * rs * gv.x + bv.x;
        float o1 = (x1 - mu) * rs * gv.y + bv.y;
        float o2 = (x2 - mu) * rs * gv.z + bv.z;
        float o3 = (x3 - mu) * rs * gv.w + bv.w;
        int grow = m0 + rr;
        if (grow < M) {
            *(float4*)(outf + (size_t)grow * 256 + lane * 4) =
                make_float4(o0, o1, o2, o3);
        }
    }
}

// ---------------- deformable sampling: quad-coop via LDS stash + pk_fma --------
__global__ __launch_bounds__(256, 6) void sample_kernel(
    const u16* __restrict__ offt, const u16* __restrict__ attnt,
    const u16* __restrict__ value, const float* __restrict__ refp,
    u16* __restrict__ samp)
{
    __shared__ uint32_t stash[256 * 17];
    int bid = blockIdx.x;                        // 6656 = 8 * 832
    int lb  = (bid & 7) * 832 + (bid >> 3);      // bijective XCD swizzle
    int bh  = lb / 208;                          // 0..31 = b*8+h
    int tblk = lb - bh * 208;
    int pr  = threadIdx.x >> 2;
    int dq  = threadIdx.x & 3;
    int tok = tblk * 64 + pr;
    if (tok >= LEN_T) return;
    int b = bh >> 3, h = bh & 7;
    size_t row = (size_t)b * LEN_T + tok;

    int W_    = dq == 0 ? 100 : dq == 1 ? 50 : dq == 2 ? 25 : 13;
    float Wf   = dq == 0 ? 100.f : dq == 1 ? 50.f : dq == 2 ? 25.f : 13.f;
    float invW = dq == 0 ? 0.01f : dq == 1 ? 0.02f : dq == 2 ? 0.04f : (1.0f / 13.0f);

    u32x2 av = __builtin_nontemporal_load(
        (const u32x2*)(attnt + ((size_t)h * M_TOK + row) * 16 + dq * 4));
    float e0 = hlo(av.x), e1 = hhi(av.x), e2 = hlo(av.y), e3 = hhi(av.y);
    float m = fmaxf(fmaxf(e0, e1), fmaxf(e2, e3));
    m = fmaxf(m, __shfl_xor(m, 1));
    m = fmaxf(m, __shfl_xor(m, 2));
    e0 = __expf(e0 - m); e1 = __expf(e1 - m);
    e2 = __expf(e2 - m); e3 = __expf(e3 - m);
    float s = e0 + e1 + e2 + e3;
    s += __shfl_xor(s, 1);
    s += __shfl_xor(s, 2);
    float inv = 1.0f / s;
    float awp[4] = {e0 * inv, e1 * inv, e2 * inv, e3 * inv};

    f32x2 rv = __builtin_nontemporal_load((const f32x2*)(refp + row * 8 + dq * 2));
    float rx = rv.x, ry = rv.y;
    u32x4 ov = __builtin_nontemporal_load(
        (const u32x4*)(offt + ((size_t)h * M_TOK + row) * 32 + dq * 8));
    float dxs[4] = {hlo(ov.x), hlo(ov.y), hlo(ov.z), hlo(ov.w)};
    float dys[4] = {hhi(ov.x), hhi(ov.y), hhi(ov.z), hhi(ov.w)};

    uint32_t* myst = stash + threadIdx.x * 17;
#pragma unroll
    for (int p = 0; p < 4; ++p) {
        float x = fmaf(fmaf(dxs[p], invW, rx), Wf, -0.5f);
        float y = fmaf(fmaf(dys[p], invW, ry), Wf, -0.5f);
        float x0f = floorf(x), y0f = floorf(y);
        int x0 = (int)x0f, y0 = (int)y0f;
        int x1 = x0 + 1, y1 = y0 + 1;
        float wx = x - x0f, wy = y - y0f;
        float vx0 = ((unsigned)x0 < (unsigned)W_) ? 1.f : 0.f;
        float vx1 = ((unsigned)x1 < (unsigned)W_) ? 1.f : 0.f;
        float vy0 = ((unsigned)y0 < (unsigned)W_) ? 1.f : 0.f;
        float vy1 = ((unsigned)y1 < (unsigned)W_) ? 1.f : 0.f;
        int cx0 = min(max(x0, 0), W_ - 1);
        int cx1 = min(max(x1, 0), W_ - 1);
        int cy0 = min(max(y0, 0), W_ - 1);
        int cy1 = min(max(y1, 0), W_ - 1);
        float a = awp[p];
        myst[p*4+0] = ((uint32_t)(cy0 * W_ + cx0) << 16) |
                      (uint32_t)f2h((1.f - wx) * (1.f - wy) * a * vx0 * vy0);
        myst[p*4+1] = ((uint32_t)(cy0 * W_ + cx1) << 16) |
                      (uint32_t)f2h(wx * (1.f - wy) * a * vx1 * vy0);
        myst[p*4+2] = ((uint32_t)(cy1 * W_ + cx0) << 16) |
                      (uint32_t)f2h((1.f - wx) * wy * a * vx0 * vy1);
        myst[p*4+3] = ((uint32_t)(cy1 * W_ + cx1) << 16) |
                      (uint32_t)f2h(wx * wy * a * vx1 * vy1);
    }

    h16x2 acch[4];
#pragma unroll
    for (int d = 0; d < 4; ++d) acch[d] = (h16x2){(_Float16)0.f, (_Float16)0.f};
    const int qb_t = threadIdx.x & ~3;

#pragma unroll
    for (int l2 = 0; l2 < 4; ++l2) {
        const int SL2 = (l2 == 0) ? 0 : (l2 == 1) ? 10000 : (l2 == 2) ? 12500 : 13125;
        const char* vbase = (const char*)(value + ((size_t)bh * LEN_T + SL2) * 32) + dq * 16;
        const uint32_t* sst = stash + (qb_t + l2) * 17;
        uint32_t pkv[16];
#pragma unroll
        for (int i = 0; i < 16; ++i) pkv[i] = sst[i];
#pragma unroll
        for (int c2 = 0; c2 < 2; ++c2) {
            u32x4 vv[8];
#pragma unroll
            for (int i = 0; i < 8; ++i) {
                uint32_t voff = (pkv[c2*8 + i] >> 10) & ~63u;   // idx*64 bytes
                vv[i] = *(const u32x4*)(vbase + voff);
            }
#pragma unroll
            for (int i = 0; i < 8; ++i) {
                uint32_t pk = pkv[c2*8 + i];
                h16x2 wp = u2h((pk << 16) | (pk & 0xffffu));
                acch[0] = __builtin_elementwise_fma(u2h(vv[i].x), wp, acch[0]);
                acch[1] = __builtin_elementwise_fma(u2h(vv[i].y), wp, acch[1]);
                acch[2] = __builtin_elementwise_fma(u2h(vv[i].z), wp, acch[2]);
                acch[3] = __builtin_elementwise_fma(u2h(vv[i].w), wp, acch[3]);
            }
        }
    }
    float a0 = (float)acch[0].x, a1 = (float)acch[0].y;
    float a2 = (float)acch[1].x, a3 = (float)acch[1].y;
    float a4 = (float)acch[2].x, a5 = (float)acch[2].y;
    float a6 = (float)acch[3].x, a7 = (float)acch[3].y;
    u32x4 uo;
    uo.x = (uint32_t)f2bf(a0) | ((uint32_t)f2bf(a1) << 16);
    uo.y = (uint32_t)f2bf(a2) | ((uint32_t)f2bf(a3) << 16);
    uo.z = (uint32_t)f2bf(a4) | ((uint32_t)f2bf(a5) << 16);
    uo.w = (uint32_t)f2bf(a6) | ((uint32_t)f2bf(a7) << 16);
    __builtin_nontemporal_store(uo, (u32x4*)(samp + row * 256 + h * 32 + dq * 8));
}

// ---------------- launcher -----------------------------------------------------
extern "C" void kernel_launch(void* const* d_in, const int* in_sizes, int n_in,
                              void* d_out, int out_size, void* d_ws, size_t ws_size,
                              hipStream_t stream)
{
    const float* features = (const float*)d_in[0];
    const float* pos      = (const float*)d_in[1];
    const float* refp     = (const float*)d_in[2];
    const float* W_off  = (const float*)d_in[5];
    const float* b_off  = (const float*)d_in[6];
    const float* W_attn = (const float*)d_in[7];
    const float* b_attn = (const float*)d_in[8];
    const float* W_val  = (const float*)d_in[9];
    const float* b_val  = (const float*)d_in[10];
    const float* W_out  = (const float*)d_in[11];
    const float* b_out  = (const float*)d_in[12];
    const float* ln1_g  = (const float*)d_in[13];
    const float* ln1_b  = (const float*)d_in[14];
    const float* W1     = (const float*)d_in[15];
    const float* b1     = (const float*)d_in[16];
    const float* W2     = (const float*)d_in[17];
    const float* b2     = (const float*)d_in[18];
    const float* ln2_g  = (const float*)d_in[19];
    const float* ln2_b  = (const float*)d_in[20];
    float* out = (float*)d_out;

    char* ws = (char*)d_ws;
    size_t o = 0;
    auto alloc = [&](size_t bytes) { char* p = ws + o; o += (bytes + 255) & ~(size_t)255; return p; };
    u16* Wt_val = (u16*)alloc((size_t)256 * 256 * 2);
    u16* Wt_oa  = (u16*)alloc((size_t)384 * 256 * 2);
    u16* Wt_out = (u16*)alloc((size_t)256 * 256 * 2);
    u16* W1f    = (u16*)alloc((size_t)1024 * 256 * 2);
    u16* W2f    = (u16*)alloc((size_t)256 * 1024 * 2);
    u16* qb     = (u16*)alloc((size_t)M_TOK * 256 * 2);   // q -> samp -> x (bf16)
    u16* fb     = (u16*)alloc((size_t)M_TOK * 256 * 2);   // features bf16
    char* big   = alloc((size_t)M_TOK * 1024 * 2);        // value|off_t|attn_t
    u16* value  = (u16*)big;                                        // f16, 27MB
    u16* offt   = (u16*)(big + (size_t)M_TOK * 256 * 2);            // f16, 27MB
    u16* attnt  = (u16*)(big + (size_t)M_TOK * 256 * 2 * 2);        // f16, 13.6MB
    u16* samp = qb;
    u16* xb   = qb;

    dim3 blk(256);
    const int mb  = (M_TOK + 127) / 128;     // 416
    const int mb64 = (M_TOK + 63) / 64;      // 831

    prep_wtrans<<<4992, blk, 0, stream>>>(
        features, pos, qb, fb, M_TOK * 256 / 4,
        W_val, W_off, W_attn, W_out, W1, W2,
        Wt_val, Wt_oa, Wt_out, W1f, W2f);

    gemm_va<<<dim3(mb, 5), blk, 0, stream>>>(
        fb, qb, Wt_val, Wt_oa, M_TOK, b_val, b_off, b_attn, value, offt, attnt);

    sample_kernel<<<6656, blk, 0, stream>>>(offt, attnt, value, refp, samp);

    // W_out GEMM + residual(features bf16) + LN1 -> xb (bf16)
    gemm_ln<4, 0><<<mb64, blk, 0, stream>>>(
        samp, Wt_out, b_out, fb, ln1_g, ln1_b, xb, nullptr, M_TOK);

    // fused FFN + residual + LN2 -> out (f32)
    ffn_fused<<<mb64, blk, 0, stream>>>(
        xb, W1f, W2f, b1, b2, ln2_g, ln2_b, out, M_TOK);
}

// Round 17
// 316.356 us; speedup vs baseline: 1.0155x; 1.0155x over previous
//
#include <hip/hip_runtime.h>
#include <stdint.h>

#define LEN_T 13294
#define M_TOK 53176   // 4 * 13294

typedef unsigned short u16;
typedef __bf16 bf16x8 __attribute__((ext_vector_type(8)));
typedef float f32x4 __attribute__((ext_vector_type(4)));
typedef float f32x2 __attribute__((ext_vector_type(2)));
typedef uint32_t u32x4 __attribute__((ext_vector_type(4)));
typedef uint32_t u32x2 __attribute__((ext_vector_type(2)));
typedef _Float16 h16x2 __attribute__((ext_vector_type(2)));

__device__ __forceinline__ u16 f2bf(float f) {
    union { float f; uint32_t u; } v; v.f = f;
    uint32_t r = v.u + 0x7fffu + ((v.u >> 16) & 1u);
    return (u16)(r >> 16);
}
__device__ __forceinline__ float bf2f(u16 s) {
    union { uint32_t u; float f; } v; v.u = ((uint32_t)s) << 16;
    return v.f;
}
__device__ __forceinline__ u16 f2h(float f) {
    union { _Float16 h; u16 u; } c; c.h = (_Float16)f; return c.u;
}
__device__ __forceinline__ float hlo(uint32_t u) {
    union { uint32_t u; _Float16 h[2]; } v; v.u = u; return (float)v.h[0];
}
__device__ __forceinline__ float hhi(uint32_t u) {
    union { uint32_t u; _Float16 h[2]; } v; v.u = u; return (float)v.h[1];
}
__device__ __forceinline__ h16x2 u2h(uint32_t u) {
    union { uint32_t u; h16x2 h; } c; c.u = u; return c.h;
}

__device__ __forceinline__ void gload_lds16(const u16* g, u16* l) {
    __builtin_amdgcn_global_load_lds(
        (const __attribute__((address_space(1))) uint32_t*)(g),
        (__attribute__((address_space(3))) uint32_t*)(l), 16, 0, 0);
}

// ---------------- prep + all weight transposes, ONE launch ---------------------
__global__ __launch_bounds__(256) void prep_wtrans(
    const float* __restrict__ feat, const float* __restrict__ pos,
    u16* __restrict__ qb, u16* __restrict__ fb, int n4,
    const float* __restrict__ W_val, const float* __restrict__ W_off,
    const float* __restrict__ W_attn, const float* __restrict__ W_out,
    const float* __restrict__ W1, const float* __restrict__ W2,
    u16* __restrict__ Wt_val, u16* __restrict__ Wt_oa,
    u16* __restrict__ Wt_out, u16* __restrict__ W1f, u16* __restrict__ W2f)
{
    if (blockIdx.x < 2048) {
        int i = blockIdx.x * 256 + threadIdx.x;
        int stride = 2048 * 256;
        for (; i < n4; i += stride) {
            float4 f = ((const float4*)feat)[i];
            float4 p = ((const float4*)pos)[i];
            uint32_t q0 = (uint32_t)f2bf(f.x + p.x) | ((uint32_t)f2bf(f.y + p.y) << 16);
            uint32_t q1 = (uint32_t)f2bf(f.z + p.z) | ((uint32_t)f2bf(f.w + p.w) << 16);
            uint32_t f0 = (uint32_t)f2bf(f.x) | ((uint32_t)f2bf(f.y) << 16);
            uint32_t f1 = (uint32_t)f2bf(f.z) | ((uint32_t)f2bf(f.w) << 16);
            ((uint2*)qb)[i] = make_uint2(q0, q1);
            ((uint2*)fb)[i] = make_uint2(f0, f1);
        }
        return;
    }
    int gid = (blockIdx.x - 2048) * 256 + threadIdx.x;
    if (gid < 229376) {
        const float* W; u16* D; int K, N, off;
        if      (gid < 65536)  { W = W_val;  D = Wt_val;        K = 256; N = 256; off = gid; }
        else if (gid < 131072) { W = W_off;  D = Wt_oa;         K = 256; N = 256; off = gid - 65536; }
        else if (gid < 163840) { W = W_attn; D = Wt_oa + 65536; K = 256; N = 128; off = gid - 131072; }
        else                   { W = W_out;  D = Wt_out;        K = 256; N = 256; off = gid - 163840; }
        int n = off / K, k = off - n * K;
        D[off] = f2bf(W[(size_t)k * N + n]);
    } else if (gid < 491520) {
        int off = gid - 229376;
        int e = off & 7, lane = (off >> 3) & 63;
        int r = off >> 9;
        int ks = r & 7, ni = (r >> 3) & 1, c = r >> 4;
        int col = c * 32 + ni * 16 + (lane & 15);
        int k = ks * 32 + (lane >> 4) * 8 + e;
        W1f[off] = f2bf(W1[(size_t)k * 1024 + col]);
    } else if (gid < 753664) {
        int off = gid - 491520;
        int e = off & 7, lane = (off >> 3) & 63;
        int r = off >> 9;
        int col = (r & 15) * 16 + (lane & 15);
        int k = (r >> 4) * 32 + (lane >> 4) * 8 + e;
        W2f[off] = f2bf(W2[(size_t)k * 256 + col]);
    }
}

// ---------------- merged VAL + OFFATTN 128x128 GEMM ----------------------------
// 1D grid 2080 = 8*260, XCD-swizzled with y-fastest order: the 5 N-tiles of
// each A-panel run consecutively on the SAME XCD -> A fetched from HBM once.
__global__ __launch_bounds__(256, 3) void gemm_va(
    const u16* __restrict__ fb, const u16* __restrict__ qb,
    const u16* __restrict__ Wt_val, const u16* __restrict__ Wt_oa,
    int M,
    const float* __restrict__ b_val, const float* __restrict__ b_off,
    const float* __restrict__ b_attn,
    u16* __restrict__ value, u16* __restrict__ offt, u16* __restrict__ attnt)
{
    __shared__ u16 Al[128 * 64];
    __shared__ u16 Bl[128 * 64];
    const int bid = blockIdx.x;                 // 2080 = 8 * 260
    const int lb  = (bid & 7) * 260 + (bid >> 3);
    const int xi  = lb / 5;
    const int yi  = lb - xi * 5;
    const int tid = threadIdx.x;
    const int lane = tid & 63;
    const int w = tid >> 6;
    const int wr = w >> 1, wc = w & 1;
    const int m0 = xi * 128;
    const bool isval = yi < 2;
    const int n0 = (isval ? yi : yi - 2) * 128;
    const u16* A  = isval ? fb : qb;
    const u16* Bt = isval ? Wt_val : Wt_oa;
    const int l15 = lane & 15;
    const int kg = lane >> 4;
    const int srow = lane >> 3;
    const int scol = (lane & 7) * 8;

    f32x4 acc[4][4];
#pragma unroll
    for (int i = 0; i < 4; ++i)
#pragma unroll
        for (int j = 0; j < 4; ++j)
            acc[i][j] = (f32x4){0.f, 0.f, 0.f, 0.f};

    for (int kc = 0; kc < 4; ++kc) {
        __syncthreads();
#pragma unroll
        for (int j = 0; j < 4; ++j) {
            int c = w * 4 + j;
            int arow = m0 + c * 8 + srow;
            arow = arow < M ? arow : M - 1;
            gload_lds16(A + (size_t)arow * 256 + (kc << 6) + scol, Al + c * 512);
            int brow = n0 + c * 8 + srow;
            gload_lds16(Bt + (size_t)brow * 256 + (kc << 6) + scol, Bl + c * 512);
        }
        __syncthreads();
#pragma unroll
        for (int ks = 0; ks < 2; ++ks) {
            bf16x8 af[4], bfr[4];
#pragma unroll
            for (int i = 0; i < 4; ++i) {
                af[i]  = *(const bf16x8*)(Al + (wr * 64 + i * 16 + l15) * 64 + ks * 32 + kg * 8);
                bfr[i] = *(const bf16x8*)(Bl + (wc * 64 + i * 16 + l15) * 64 + ks * 32 + kg * 8);
            }
#pragma unroll
            for (int mi = 0; mi < 4; ++mi)
#pragma unroll
                for (int ni = 0; ni < 4; ++ni)
                    acc[mi][ni] = __builtin_amdgcn_mfma_f32_16x16x32_bf16(
                        af[mi], bfr[ni], acc[mi][ni], 0, 0, 0);
        }
    }

#pragma unroll
    for (int mi = 0; mi < 4; ++mi) {
#pragma unroll
        for (int r = 0; r < 4; ++r) {
            int row = m0 + wr * 64 + mi * 16 + kg * 4 + r;
            if (row >= M) continue;
#pragma unroll
            for (int ni = 0; ni < 4; ++ni) {
                int col = n0 + wc * 64 + ni * 16 + l15;
                float v = acc[mi][ni][r];
                if (isval) {
                    int bI = row / LEN_T;
                    int t = row - bI * LEN_T;
                    int hh = col >> 5, d = col & 31;
                    value[((size_t)(bI * 8 + hh) * LEN_T + t) * 32 + d] =
                        f2h(v + b_val[col]);
                } else {
                    if (col < 256) {
                        offt[((size_t)(col >> 5) * M_TOK + row) * 32 + (col & 31)] =
                            f2h(v + b_off[col]);
                    } else {
                        int c = col - 256;
                        attnt[((size_t)(c >> 4) * M_TOK + row) * 16 + (c & 15)] =
                            f2h(v + b_attn[c]);
                    }
                }
            }
        }
    }
}

// ---------------- 64-row GEMM + LayerNorm epilogue (W_out + LN1), bf16 dump ----
template<int KSTEPS, int OUTF32>
__global__ __launch_bounds__(256, 3) void gemm_ln(
    const u16* __restrict__ A, const u16* __restrict__ Bt,
    const float* __restrict__ bias, const u16* __restrict__ res,
    const float* __restrict__ g, const float* __restrict__ bb,
    u16* __restrict__ outb, float* __restrict__ outf, int M)
{
    __shared__ char ldsraw[40960];
    u16* Al = (u16*)ldsraw;                 // [64][64]
    u16* Bl = (u16*)(ldsraw + 8192);        // [256][64]
    u16* dumpb = (u16*)ldsraw;              // [64][264] bf16 (aliases stage bufs)
    const int tid = threadIdx.x;
    const int lane = tid & 63;
    const int w = tid >> 6;
    const int l15 = lane & 15;
    const int kg = lane >> 4;
    const int srow = lane >> 3;
    const int scol = (lane & 7) * 8;
    const int m0 = blockIdx.x * 64;
    const int K = KSTEPS * 64;

    f32x4 acc[4][4];
#pragma unroll
    for (int i = 0; i < 4; ++i)
#pragma unroll
        for (int j = 0; j < 4; ++j)
            acc[i][j] = (f32x4){0.f, 0.f, 0.f, 0.f};

    for (int kc = 0; kc < KSTEPS; ++kc) {
        __syncthreads();
#pragma unroll
        for (int j = 0; j < 2; ++j) {
            int c = w * 2 + j;
            int arow = m0 + c * 8 + srow;
            arow = arow < M ? arow : M - 1;
            gload_lds16(A + (size_t)arow * K + (kc << 6) + scol, Al + c * 512);
        }
#pragma unroll
        for (int j = 0; j < 8; ++j) {
            int c = w * 8 + j;
            int brow = c * 8 + srow;
            gload_lds16(Bt + (size_t)brow * K + (kc << 6) + scol, Bl + c * 512);
        }
        __syncthreads();
#pragma unroll
        for (int ks = 0; ks < 2; ++ks) {
            bf16x8 af[4], bfr[4];
#pragma unroll
            for (int i = 0; i < 4; ++i) {
                af[i]  = *(const bf16x8*)(Al + (i * 16 + l15) * 64 + ks * 32 + kg * 8);
                bfr[i] = *(const bf16x8*)(Bl + (w * 64 + i * 16 + l15) * 64 + ks * 32 + kg * 8);
            }
#pragma unroll
            for (int mi = 0; mi < 4; ++mi)
#pragma unroll
                for (int ni = 0; ni < 4; ++ni)
                    acc[mi][ni] = __builtin_amdgcn_mfma_f32_16x16x32_bf16(
                        af[mi], bfr[ni], acc[mi][ni], 0, 0, 0);
        }
    }

    __syncthreads();   // staging reads done before dump overwrites Al/Bl
#pragma unroll
    for (int mi = 0; mi < 4; ++mi) {
#pragma unroll
        for (int r = 0; r < 4; ++r) {
            int rr = mi * 16 + kg * 4 + r;
            int gr = m0 + rr; gr = gr < M ? gr : M - 1;
#pragma unroll
            for (int ni = 0; ni < 4; ++ni) {
                int col = w * 64 + ni * 16 + l15;
                dumpb[rr * 264 + col] = f2bf(acc[mi][ni][r] + bias[col] +
                                             bf2f(res[(size_t)gr * 256 + col]));
            }
        }
    }
    __syncthreads();

    float4 gv = *(const float4*)(g + lane * 4);
    float4 bv = *(const float4*)(bb + lane * 4);
#pragma unroll
    for (int i = 0; i < 16; ++i) {
        int rr = w * 16 + i;
        uint2 raw = *(const uint2*)(dumpb + rr * 264 + lane * 4);
        float x0 = bf2f((u16)(raw.x & 0xffff)), x1 = bf2f((u16)(raw.x >> 16));
        float x2 = bf2f((u16)(raw.y & 0xffff)), x3 = bf2f((u16)(raw.y >> 16));
        float s1 = x0 + x1 + x2 + x3;
        float s2 = x0*x0 + x1*x1 + x2*x2 + x3*x3;
#pragma unroll
        for (int o = 1; o < 64; o <<= 1) {
            s1 += __shfl_xor(s1, o);
            s2 += __shfl_xor(s2, o);
        }
        float mu = s1 * (1.0f / 256.0f);
        float var = s2 * (1.0f / 256.0f) - mu * mu;
        float rs = rsqrtf(var + 1e-5f);
        float o0 = (x0 - mu) * rs * gv.x + bv.x;
        float o1 = (x1 - mu) * rs * gv.y + bv.y;
        float o2 = (x2 - mu) * rs * gv.z + bv.z;
        float o3 = (x3 - mu) * rs * gv.w + bv.w;
        int grow = m0 + rr;
        if (grow < M) {
            if (OUTF32) {
                *(float4*)(outf + (size_t)grow * 256 + lane * 4) =
                    make_float4(o0, o1, o2, o3);
            } else {
                uint32_t u0 = (uint32_t)f2bf(o0) | ((uint32_t)f2bf(o1) << 16);
                uint32_t u1 = (uint32_t)f2bf(o2) | ((uint32_t)f2bf(o3) << 16);
                *(uint2*)(outb + (size_t)grow * 256 + lane * 4) = make_uint2(u0, u1);
            }
        }
    }
}

// ---------------- fused FFN (round-9 proven structure) -------------------------
__global__ __launch_bounds__(256, 3) void ffn_fused(
    const u16* __restrict__ A, const u16* __restrict__ W1f, const u16* __restrict__ W2f,
    const float* __restrict__ b1, const float* __restrict__ b2,
    const float* __restrict__ g, const float* __restrict__ bb,
    float* __restrict__ outf, int M)
{
    __shared__ char lds[51200];
    u16* Axl = (u16*)lds;                 // [64][264] bf16 (x staging + residual)
    u16* ht  = (u16*)(lds + 33792);       // [64][136] bf16
    u16* dumpb = (u16*)lds;               // [64][264] bf16 (aliases Axl)
    const int tid = threadIdx.x;
    const int lane = tid & 63;
    const int w = tid >> 6;
    const int l15 = lane & 15;
    const int kg = lane >> 4;
    const int m0 = blockIdx.x * 64;

#pragma unroll
    for (int i = 0; i < 8; ++i) {
        int linear = i * 256 + tid;
        int row = linear >> 5;
        int gcol = (linear & 31) * 8;
        int grow = m0 + row; grow = grow < M ? grow : M - 1;
        uint4 v = *(const uint4*)(A + (size_t)grow * 256 + gcol);
        *(uint4*)(Axl + row * 264 + gcol) = v;
    }
    __syncthreads();

    f32x4 acc[4][4];
#pragma unroll
    for (int i = 0; i < 4; ++i)
#pragma unroll
        for (int j = 0; j < 4; ++j)
            acc[i][j] = (f32x4){0.f, 0.f, 0.f, 0.f};
    f32x4 acc2[4][2];

#define ZERO_ACC2() \
    _Pragma("unroll") for (int i = 0; i < 4; ++i) { \
        acc2[i][0] = (f32x4){0.f,0.f,0.f,0.f}; acc2[i][1] = (f32x4){0.f,0.f,0.f,0.f}; }

#define FFN1_CHUNK(HC) { \
    _Pragma("unroll") for (int ks = 0; ks < 8; ++ks) { \
        bf16x8 af[4], bw[2]; \
        _Pragma("unroll") for (int ni = 0; ni < 2; ++ni) \
            bw[ni] = *(const bf16x8*)(W1f + ((size_t)(((((HC) * 4 + w) * 2 + ni) * 8 + ks)) << 9) + lane * 8); \
        _Pragma("unroll") for (int mi = 0; mi < 4; ++mi) \
            af[mi] = *(const bf16x8*)(Axl + (mi * 16 + l15) * 264 + ks * 32 + kg * 8); \
        _Pragma("unroll") for (int mi = 0; mi < 4; ++mi) \
            _Pragma("unroll") for (int ni = 0; ni < 2; ++ni) \
                acc2[mi][ni] = __builtin_amdgcn_mfma_f32_16x16x32_bf16(af[mi], bw[ni], acc2[mi][ni], 0, 0, 0); \
    } }

#define FFN2_CHUNK(HC) { \
    _Pragma("unroll") for (int ks2 = 0; ks2 < 4; ++ks2) { \
        bf16x8 ah[4], bw2[4]; \
        _Pragma("unroll") for (int ni = 0; ni < 4; ++ni) \
            bw2[ni] = *(const bf16x8*)(W2f + ((size_t)((((HC) * 4 + ks2) * 16 + w * 4 + ni)) << 9) + lane * 8); \
        _Pragma("unroll") for (int mi = 0; mi < 4; ++mi) \
            ah[mi] = *(const bf16x8*)(ht + (mi * 16 + l15) * 136 + ks2 * 32 + kg * 8); \
        _Pragma("unroll") for (int mi = 0; mi < 4; ++mi) \
            _Pragma("unroll") for (int ni = 0; ni < 4; ++ni) \
                acc[mi][ni] = __builtin_amdgcn_mfma_f32_16x16x32_bf16(ah[mi], bw2[ni], acc[mi][ni], 0, 0, 0); \
    } }

#define HT_WRITE(HC) { \
    _Pragma("unroll") for (int mi = 0; mi < 4; ++mi) \
        _Pragma("unroll") for (int ni = 0; ni < 2; ++ni) \
            _Pragma("unroll") for (int r = 0; r < 4; ++r) { \
                int rr = mi * 16 + kg * 4 + r; \
                int cl = w * 32 + ni * 16 + l15; \
                float hv = acc2[mi][ni][r] + b1[(HC) * 128 + cl]; \
                ht[rr * 136 + cl] = f2bf(hv > 0.f ? hv : 0.f); \
            } }

    ZERO_ACC2();
    FFN1_CHUNK(0);
    for (int hc = 0; hc < 8; ++hc) {
        __syncthreads();
        HT_WRITE(hc);
        __syncthreads();
        FFN2_CHUNK(hc);
        if (hc < 7) { ZERO_ACC2(); FFN1_CHUNK(hc + 1); }
    }

#pragma unroll
    for (int mi = 0; mi < 4; ++mi) {
#pragma unroll
        for (int r = 0; r < 4; ++r) {
            int rr = mi * 16 + kg * 4 + r;
#pragma unroll
            for (int ni = 0; ni < 4; ++ni) {
                int col = w * 64 + ni * 16 + l15;
                float v = acc[mi][ni][r] + b2[col] + bf2f(Axl[rr * 264 + col]);
                dumpb[rr * 264 + col] = f2bf(v);
            }
        }
    }
    __syncthreads();

    float4 gv = *(const float4*)(g + lane * 4);
    float4 bv = *(const float4*)(bb + lane * 4);
#pragma unroll
    for (int i = 0; i < 16; ++i) {
        int rr = w * 16 + i;
        uint2 raw = *(const uint2*)(dumpb + rr * 264 + lane * 4);
        float x0 = bf2f((u16)(raw.x & 0xffff)), x1 = bf2f((u16)(raw.x >> 16));
        float x2 = bf2f((u16)(raw.y & 0xffff)), x3 = bf2f((u16)(raw.y >> 16));
        float s1 = x0 + x1 + x2 + x3;
        float s2 = x0*x0 + x1*x1 + x2*x2 + x3*x3;
#pragma unroll
        for (int o = 1; o < 64; o <<= 1) {
            s1 += __shfl_xor(s1, o);
            s2 += __shfl_xor(s2, o);
        }
        float mu = s1 * (1.0f / 256.0f);
        float var = s2 * (1.0f / 256.0f) - mu * mu;
        float rs = rsqrtf(var + 1e-5f);
        float o0 = (x0 - mu) * rs * gv.x + bv.x;
        float o1 = (x1 - mu) * rs * gv.y + bv.y;
        float o2 = (x2 - mu) * rs * gv.z + bv.z;
        float o3 = (x3 - mu) * rs * gv.w + bv.w;
        int grow = m0 + rr;
        if (grow < M) {
            *(float4*)(outf + (size_t)grow * 256 + lane * 4) =
                make_float4(o0, o1, o2, o3);
        }
    }
}

// ---------------- deformable sampling: quad-coop via LDS stash + pk_fma --------
__global__ __launch_bounds__(256, 4) void sample_kernel(
    const u16* __restrict__ offt, const u16* __restrict__ attnt,
    const u16* __restrict__ value, const float* __restrict__ refp,
    u16* __restrict__ samp)
{
    __shared__ uint32_t stash[256 * 17];
    int bid = blockIdx.x;                        // 6656 = 8 * 832
    int lb  = (bid & 7) * 832 + (bid >> 3);      // bijective XCD swizzle
    int bh  = lb / 208;                          // 0..31 = b*8+h
    int tblk = lb - bh * 208;
    int pr  = threadIdx.x >> 2;
    int dq  = threadIdx.x & 3;
    int tok = tblk * 64 + pr;
    if (tok >= LEN_T) return;
    int b = bh >> 3, h = bh & 7;
    size_t row = (size_t)b * LEN_T + tok;

    int W_    = dq == 0 ? 100 : dq == 1 ? 50 : dq == 2 ? 25 : 13;
    float Wf   = dq == 0 ? 100.f : dq == 1 ? 50.f : dq == 2 ? 25.f : 13.f;
    float invW = dq == 0 ? 0.01f : dq == 1 ? 0.02f : dq == 2 ? 0.04f : (1.0f / 13.0f);

    u32x2 av = __builtin_nontemporal_load(
        (const u32x2*)(attnt + ((size_t)h * M_TOK + row) * 16 + dq * 4));
    float e0 = hlo(av.x), e1 = hhi(av.x), e2 = hlo(av.y), e3 = hhi(av.y);
    float m = fmaxf(fmaxf(e0, e1), fmaxf(e2, e3));
    m = fmaxf(m, __shfl_xor(m, 1));
    m = fmaxf(m, __shfl_xor(m, 2));
    e0 = __expf(e0 - m); e1 = __expf(e1 - m);
    e2 = __expf(e2 - m); e3 = __expf(e3 - m);
    float s = e0 + e1 + e2 + e3;
    s += __shfl_xor(s, 1);
    s += __shfl_xor(s, 2);
    float inv = 1.0f / s;
    float awp[4] = {e0 * inv, e1 * inv, e2 * inv, e3 * inv};

    f32x2 rv = __builtin_nontemporal_load((const f32x2*)(refp + row * 8 + dq * 2));
    float rx = rv.x, ry = rv.y;
    u32x4 ov = __builtin_nontemporal_load(
        (const u32x4*)(offt + ((size_t)h * M_TOK + row) * 32 + dq * 8));
    float dxs[4] = {hlo(ov.x), hlo(ov.y), hlo(ov.z), hlo(ov.w)};
    float dys[4] = {hhi(ov.x), hhi(ov.y), hhi(ov.z), hhi(ov.w)};

    uint32_t* myst = stash + threadIdx.x * 17;
#pragma unroll
    for (int p = 0; p < 4; ++p) {
        float x = fmaf(fmaf(dxs[p], invW, rx), Wf, -0.5f);
        float y = fmaf(fmaf(dys[p], invW, ry), Wf, -0.5f);
        float x0f = floorf(x), y0f = floorf(y);
        int x0 = (int)x0f, y0 = (int)y0f;
        int x1 = x0 + 1, y1 = y0 + 1;
        float wx = x - x0f, wy = y - y0f;
        float vx0 = ((unsigned)x0 < (unsigned)W_) ? 1.f : 0.f;
        float vx1 = ((unsigned)x1 < (unsigned)W_) ? 1.f : 0.f;
        float vy0 = ((unsigned)y0 < (unsigned)W_) ? 1.f : 0.f;
        float vy1 = ((unsigned)y1 < (unsigned)W_) ? 1.f : 0.f;
        int cx0 = min(max(x0, 0), W_ - 1);
        int cx1 = min(max(x1, 0), W_ - 1);
        int cy0 = min(max(y0, 0), W_ - 1);
        int cy1 = min(max(y1, 0), W_ - 1);
        float a = awp[p];
        myst[p*4+0] = ((uint32_t)(cy0 * W_ + cx0) << 16) |
                      (uint32_t)f2h((1.f - wx) * (1.f - wy) * a * vx0 * vy0);
        myst[p*4+1] = ((uint32_t)(cy0 * W_ + cx1) << 16) |
                      (uint32_t)f2h(wx * (1.f - wy) * a * vx1 * vy0);
        myst[p*4+2] = ((uint32_t)(cy1 * W_ + cx0) << 16) |
                      (uint32_t)f2h((1.f - wx) * wy * a * vx0 * vy1);
        myst[p*4+3] = ((uint32_t)(cy1 * W_ + cx1) << 16) |
                      (uint32_t)f2h(wx * wy * a * vx1 * vy1);
    }

    h16x2 acch[4];
#pragma unroll
    for (int d = 0; d < 4; ++d) acch[d] = (h16x2){(_Float16)0.f, (_Float16)0.f};
    const int qb_t = threadIdx.x & ~3;

#pragma unroll
    for (int l2 = 0; l2 < 4; ++l2) {
        const int SL2 = (l2 == 0) ? 0 : (l2 == 1) ? 10000 : (l2 == 2) ? 12500 : 13125;
        const char* vbase = (const char*)(value + ((size_t)bh * LEN_T + SL2) * 32) + dq * 16;
        const uint32_t* sst = stash + (qb_t + l2) * 17;
        uint32_t pkv[16];
#pragma unroll
        for (int i = 0; i < 16; ++i) pkv[i] = sst[i];
#pragma unroll
        for (int c2 = 0; c2 < 2; ++c2) {
            u32x4 vv[8];
#pragma unroll
            for (int i = 0; i < 8; ++i) {
                uint32_t voff = (pkv[c2*8 + i] >> 10) & ~63u;   // idx*64 bytes
                vv[i] = *(const u32x4*)(vbase + voff);
            }
#pragma unroll
            for (int i = 0; i < 8; ++i) {
                uint32_t pk = pkv[c2*8 + i];
                h16x2 wp = u2h((pk << 16) | (pk & 0xffffu));
                acch[0] = __builtin_elementwise_fma(u2h(vv[i].x), wp, acch[0]);
                acch[1] = __builtin_elementwise_fma(u2h(vv[i].y), wp, acch[1]);
                acch[2] = __builtin_elementwise_fma(u2h(vv[i].z), wp, acch[2]);
                acch[3] = __builtin_elementwise_fma(u2h(vv[i].w), wp, acch[3]);
            }
        }
    }
    float a0 = (float)acch[0].x, a1 = (float)acch[0].y;
    float a2 = (float)acch[1].x, a3 = (float)acch[1].y;
    float a4 = (float)acch[2].x, a5 = (float)acch[2].y;
    float a6 = (float)acch[3].x, a7 = (float)acch[3].y;
    u32x4 uo;
    uo.x = (uint32_t)f2bf(a0) | ((uint32_t)f2bf(a1) << 16);
    uo.y = (uint32_t)f2bf(a2) | ((uint32_t)f2bf(a3) << 16);
    uo.z = (uint32_t)f2bf(a4) | ((uint32_t)f2bf(a5) << 16);
    uo.w = (uint32_t)f2bf(a6) | ((uint32_t)f2bf(a7) << 16);
    __builtin_nontemporal_store(uo, (u32x4*)(samp + row * 256 + h * 32 + dq * 8));
}

// ---------------- launcher -----------------------------------------------------
extern "C" void kernel_launch(void* const* d_in, const int* in_sizes, int n_in,
                              void* d_out, int out_size, void* d_ws, size_t ws_size,
                              hipStream_t stream)
{
    const float* features = (const float*)d_in[0];
    const float* pos      = (const float*)d_in[1];
    const float* refp     = (const float*)d_in[2];
    const float* W_off  = (const float*)d_in[5];
    const float* b_off  = (const float*)d_in[6];
    const float* W_attn = (const float*)d_in[7];
    const float* b_attn = (const float*)d_in[8];
    const float* W_val  = (const float*)d_in[9];
    const float* b_val  = (const float*)d_in[10];
    const float* W_out  = (const float*)d_in[11];
    const float* b_out  = (const float*)d_in[12];
    const float* ln1_g  = (const float*)d_in[13];
    const float* ln1_b  = (const float*)d_in[14];
    const float* W1     = (const float*)d_in[15];
    const float* b1     = (const float*)d_in[16];
    const float* W2     = (const float*)d_in[17];
    const float* b2     = (const float*)d_in[18];
    const float* ln2_g  = (const float*)d_in[19];
    const float* ln2_b  = (const float*)d_in[20];
    float* out = (float*)d_out;

    char* ws = (char*)d_ws;
    size_t o = 0;
    auto alloc = [&](size_t bytes) { char* p = ws + o; o += (bytes + 255) & ~(size_t)255; return p; };
    u16* Wt_val = (u16*)alloc((size_t)256 * 256 * 2);
    u16* Wt_oa  = (u16*)alloc((size_t)384 * 256 * 2);
    u16* Wt_out = (u16*)alloc((size_t)256 * 256 * 2);
    u16* W1f    = (u16*)alloc((size_t)1024 * 256 * 2);
    u16* W2f    = (u16*)alloc((size_t)256 * 1024 * 2);
    u16* qb     = (u16*)alloc((size_t)M_TOK * 256 * 2);   // q -> samp -> x (bf16)
    u16* fb     = (u16*)alloc((size_t)M_TOK * 256 * 2);   // features bf16
    char* big   = alloc((size_t)M_TOK * 1024 * 2);        // value|off_t|attn_t
    u16* value  = (u16*)big;                                        // f16, 27MB
    u16* offt   = (u16*)(big + (size_t)M_TOK * 256 * 2);            // f16, 27MB
    u16* attnt  = (u16*)(big + (size_t)M_TOK * 256 * 2 * 2);        // f16, 13.6MB
    u16* samp = qb;
    u16* xb   = qb;

    dim3 blk(256);
    const int mb  = (M_TOK + 127) / 128;     // 416
    const int mb64 = (M_TOK + 63) / 64;      // 831

    prep_wtrans<<<4992, blk, 0, stream>>>(
        features, pos, qb, fb, M_TOK * 256 / 4,
        W_val, W_off, W_attn, W_out, W1, W2,
        Wt_val, Wt_oa, Wt_out, W1f, W2f);

    gemm_va<<<2080, blk, 0, stream>>>(
        fb, qb, Wt_val, Wt_oa, M_TOK, b_val, b_off, b_attn, value, offt, attnt);

    sample_kernel<<<6656, blk, 0, stream>>>(offt, attnt, value, refp, samp);

    // W_out GEMM + residual(features bf16) + LN1 -> xb (bf16)
    gemm_ln<4, 0><<<mb64, blk, 0, stream>>>(
        samp, Wt_out, b_out, fb, ln1_g, ln1_b, xb, nullptr, M_TOK);

    // fused FFN + residual + LN2 -> out (f32)
    ffn_fused<<<mb64, blk, 0, stream>>>(
        xb, W1f, W2f, b1, b2, ln2_g, ln2_b, out, M_TOK);
}